// Round 1
// baseline (403.433 us; speedup 1.0000x reference)
//
#include <hip/hip_runtime.h>
#include <hip/hip_bf16.h>

// Problem constants (from reference setup_inputs)
#define B_  128
#define J_  4096
#define D_  64
#define H_  128
#define E_  256
#define Z_  32

// ---------------------------------------------------------------------------
// Kernel A: G[j][h] = hb1[h] + sum_d F[j][d] * hW1[1+d][h]
// plus per-j LN1 statistics: Gstats[j] = {mean_h(G), mean_h(w0*G), mean_h(G^2)}
// where w0[h] = hW1[0][h].
// One block (128 threads = 2 waves) per j.
// ---------------------------------------------------------------------------
__global__ __launch_bounds__(128) void g_kernel(
    const float* __restrict__ F, const float* __restrict__ hW1,
    const float* __restrict__ hb1, float* __restrict__ G,
    float4* __restrict__ Gstats)
{
    int j = blockIdx.x;
    int h = threadIdx.x;
    const float* frow = F + (size_t)j * D_;
    float acc = hb1[h];
#pragma unroll
    for (int d = 0; d < D_; d++)
        acc = fmaf(frow[d], hW1[(size_t)(d + 1) * H_ + h], acc);
    G[(size_t)j * H_ + h] = acc;

    float w0h = hW1[h];                    // row 0 of hW1
    float s1 = acc, s2 = w0h * acc, s3 = acc * acc;
#pragma unroll
    for (int off = 32; off; off >>= 1) {
        s1 += __shfl_xor(s1, off);
        s2 += __shfl_xor(s2, off);
        s3 += __shfl_xor(s3, off);
    }
    __shared__ float red[6];
    if ((h & 63) == 0) {
        int w = h >> 6;
        red[w * 3 + 0] = s1; red[w * 3 + 1] = s2; red[w * 3 + 2] = s3;
    }
    __syncthreads();
    if (h == 0) {
        float a = red[0] + red[3];
        float b = red[1] + red[4];
        float c = red[2] + red[5];
        const float inv = 1.f / (float)H_;
        Gstats[j] = make_float4(a * inv, b * inv, c * inv, 0.f);
    }
}

// ---------------------------------------------------------------------------
// Kernel B (dominant): per-(b,j) fused  LN1 -> ReLU -> (128x64 matvec) -> LN2
// -> ReLU -> masked accumulate into pooled[b][d].
// One wave (64 threads) per block; JPB rows per block.
// Lane d holds W2 column d (32 x float4 = 128 VGPRs).
// Lane l holds h-elements 2l, 2l+1 (float2 layout end-to-end).
// ---------------------------------------------------------------------------
#define JPB 128

__global__ __launch_bounds__(64) void main_kernel(
    const float* __restrict__ x, const int* __restrict__ mask,
    const float* __restrict__ G, const float4* __restrict__ Gstats,
    const float* __restrict__ hW1,
    const float* __restrict__ hg1, const float* __restrict__ hbt1,
    const float* __restrict__ hW2, const float* __restrict__ hb2,
    const float* __restrict__ hg2, const float* __restrict__ hbt2,
    float* __restrict__ pooled, float* __restrict__ cntg)
{
    __shared__ float lds_h[H_];
    const int lane = threadIdx.x;           // 0..63
    const int b    = blockIdx.y;
    const int j0   = blockIdx.x * JPB;

    // ---- per-block preload ----
    float4 w2r[32];                          // W2[4i+k][lane], k=0..3
#pragma unroll
    for (int i = 0; i < 32; i++) {
        w2r[i].x = hW2[(size_t)(4 * i + 0) * D_ + lane];
        w2r[i].y = hW2[(size_t)(4 * i + 1) * D_ + lane];
        w2r[i].z = hW2[(size_t)(4 * i + 2) * D_ + lane];
        w2r[i].w = hW2[(size_t)(4 * i + 3) * D_ + lane];
    }
    float2 w0 = ((const float2*)hW1)[lane];   // hW1 row 0 elems 2l, 2l+1
    float2 g1 = ((const float2*)hg1)[lane];
    float2 b1 = ((const float2*)hbt1)[lane];
    float  b2v  = hb2[lane];
    float  g2v  = hg2[lane];
    float  bt2v = hbt2[lane];

    // scalar LN1 stats of w0: mean(w0), mean(w0^2) (wave allreduce, once)
    float a = w0.x + w0.y;
    float q = w0.x * w0.x + w0.y * w0.y;
#pragma unroll
    for (int off = 32; off; off >>= 1) {
        a += __shfl_xor(a, off);
        q += __shfl_xor(q, off);
    }
    const float mw0  = a * (1.f / (float)H_);
    const float ew02 = q * (1.f / (float)H_);

    float pool = 0.f;
    int   cn   = 0;

    for (int jj = 0; jj < JPB; jj++) {
        const int j = j0 + jj;
        const float xv = x[(size_t)b * J_ + j];          // uniform
        const int   mk = mask[(size_t)b * J_ + j];       // uniform
        const float2 g = ((const float2*)G)[(size_t)j * (H_ / 2) + lane];
        const float4 gs = Gstats[j];                     // uniform

        // LN1 statistics closed-form in x
        const float mean = fmaf(xv, mw0, gs.x);
        const float eh2  = fmaf(xv, fmaf(xv, ew02, 2.f * gs.y), gs.z);
        const float var  = fmaf(-mean, mean, eh2);
        const float r    = rsqrtf(var + 1e-5f);

        const float p0 = fmaf(xv, w0.x, g.x);
        const float p1 = fmaf(xv, w0.y, g.y);
        const float h0 = fmaxf(0.f, fmaf((p0 - mean) * r, g1.x, b1.x));
        const float h1 = fmaxf(0.f, fmaf((p1 - mean) * r, g1.y, b1.y));

        __syncthreads();                                  // prev-iter reads done
        ((float2*)lds_h)[lane] = make_float2(h0, h1);
        __syncthreads();                                  // writes visible

        // matvec: h2[lane] = hb2[lane] + sum_h h[h] * W2[h][lane]
        float acc = b2v;
#pragma unroll
        for (int i = 0; i < 32; i++) {
            const float4 hv = ((const float4*)lds_h)[i];  // broadcast read
            acc = fmaf(hv.x, w2r[i].x, acc);
            acc = fmaf(hv.y, w2r[i].y, acc);
            acc = fmaf(hv.z, w2r[i].z, acc);
            acc = fmaf(hv.w, w2r[i].w, acc);
        }

        // LN2 over 64 lanes
        float s = acc, s2 = acc * acc;
#pragma unroll
        for (int off = 32; off; off >>= 1) {
            s  += __shfl_xor(s, off);
            s2 += __shfl_xor(s2, off);
        }
        const float m2 = s * (1.f / (float)D_);
        const float v2 = fmaf(-m2, m2, s2 * (1.f / (float)D_));
        const float r2 = rsqrtf(v2 + 1e-5f);
        const float o  = fmaxf(0.f, fmaf((acc - m2) * r2, g2v, bt2v));

        if (mk) { pool += o; cn++; }
    }

    atomicAdd(&pooled[(size_t)b * D_ + lane], pool);
    if (lane == 0) atomicAdd(&cntg[b], (float)cn);
}

// ---------------------------------------------------------------------------
// Kernel C: per-b head. c = pooled/cnt; e = relu(ln_na(c@eW1+eb1));
// out = relu(ln_na(e@eW2+eb2)); split into mu / logvar.
// One block (256 threads) per b.
// ---------------------------------------------------------------------------
__global__ __launch_bounds__(256) void final_kernel(
    const float* __restrict__ pooled, const float* __restrict__ cntg,
    const float* __restrict__ eW1, const float* __restrict__ eb1,
    const float* __restrict__ eW2, const float* __restrict__ eb2,
    float* __restrict__ out)
{
    __shared__ float c_lds[D_];
    __shared__ float e_lds[E_];
    __shared__ float red[8];
    const int b = blockIdx.x;
    const int t = threadIdx.x;

    if (t < D_) {
        float cn = fmaxf(cntg[b], 1.f);
        c_lds[t] = pooled[(size_t)b * D_ + t] / cn;
    }
    __syncthreads();

    // layer 1: 64 -> 256
    float acc = eb1[t];
#pragma unroll
    for (int d = 0; d < D_; d++)
        acc = fmaf(c_lds[d], eW1[(size_t)d * E_ + t], acc);

    // block LN over 256 (no affine)
    float s = acc, s2 = acc * acc;
#pragma unroll
    for (int off = 32; off; off >>= 1) {
        s  += __shfl_xor(s, off);
        s2 += __shfl_xor(s2, off);
    }
    const int wid = t >> 6;
    if ((t & 63) == 0) { red[wid * 2] = s; red[wid * 2 + 1] = s2; }
    __syncthreads();
    s  = red[0] + red[2] + red[4] + red[6];
    s2 = red[1] + red[3] + red[5] + red[7];
    const float m = s * (1.f / (float)E_);
    const float v = fmaf(-m, m, s2 * (1.f / (float)E_));
    const float r = rsqrtf(v + 1e-5f);
    e_lds[t] = fmaxf(0.f, (acc - m) * r);
    __syncthreads();

    // layer 2: 256 -> 64, first wave only
    if (t < 64) {
        float a2 = eb2[t];
#pragma unroll 8
        for (int k = 0; k < E_; k++)
            a2 = fmaf(e_lds[k], eW2[(size_t)k * 64 + t], a2);

        float u = a2, u2 = a2 * a2;
#pragma unroll
        for (int off = 32; off; off >>= 1) {
            u  += __shfl_xor(u, off);
            u2 += __shfl_xor(u2, off);
        }
        const float m2 = u * (1.f / 64.f);
        const float v2 = fmaf(-m2, m2, u2 * (1.f / 64.f));
        const float r2 = rsqrtf(v2 + 1e-5f);
        const float o  = fmaxf(0.f, (a2 - m2) * r2);
        if (t < Z_) out[(size_t)b * Z_ + t] = o;                       // mu
        else        out[(size_t)B_ * Z_ + (size_t)b * Z_ + (t - Z_)] = o; // logvar
    }
}

// ---------------------------------------------------------------------------
extern "C" void kernel_launch(void* const* d_in, const int* in_sizes, int n_in,
                              void* d_out, int out_size, void* d_ws, size_t ws_size,
                              hipStream_t stream) {
    const float* x    = (const float*)d_in[0];
    const int*   mask = (const int*)d_in[1];
    const float* F    = (const float*)d_in[2];
    const float* hW1  = (const float*)d_in[3];
    const float* hb1  = (const float*)d_in[4];
    const float* hg1  = (const float*)d_in[5];
    const float* hbt1 = (const float*)d_in[6];
    const float* hW2  = (const float*)d_in[7];
    const float* hb2  = (const float*)d_in[8];
    const float* hg2  = (const float*)d_in[9];
    const float* hbt2 = (const float*)d_in[10];
    const float* eW1  = (const float*)d_in[11];
    const float* eb1  = (const float*)d_in[12];
    const float* eW2  = (const float*)d_in[13];
    const float* eb2  = (const float*)d_in[14];
    float* out = (float*)d_out;

    // workspace layout
    char* ws = (char*)d_ws;
    float*  G      = (float*)(ws);                                  // 4096*128*4 = 2 MiB
    float4* Gstats = (float4*)(ws + (size_t)J_ * H_ * 4);           // 64 KiB
    float*  pooled = (float*)(ws + (size_t)J_ * H_ * 4 + (size_t)J_ * 16);         // 32 KiB
    float*  cntg   = (float*)(ws + (size_t)J_ * H_ * 4 + (size_t)J_ * 16 + (size_t)B_ * D_ * 4);

    // zero accumulators (ws is poisoned 0xAA before every launch)
    hipMemsetAsync(pooled, 0, (size_t)B_ * D_ * 4 + (size_t)B_ * 4, stream);

    g_kernel<<<J_, H_, 0, stream>>>(F, hW1, hb1, G, Gstats);

    dim3 grid(J_ / JPB, B_);
    main_kernel<<<grid, 64, 0, stream>>>(x, mask, G, Gstats, hW1, hg1, hbt1,
                                         hW2, hb2, hg2, hbt2, pooled, cntg);

    final_kernel<<<B_, E_, 0, stream>>>(pooled, cntg, eW1, eb1, eW2, eb2, out);
}

// Round 2
// 173.811 us; speedup vs baseline: 2.3211x; 2.3211x over previous
//
#include <hip/hip_runtime.h>
#include <hip/hip_bf16.h>

#define B_  128
#define J_  4096
#define D_  64
#define H_  128
#define E_  256
#define Z_  32

typedef __attribute__((ext_vector_type(8))) short short8;    // 8 bf16 (4 VGPRs)
typedef __attribute__((ext_vector_type(4))) float floatx4;   // MFMA C/D

// workspace layout (bytes)
#define OFF_G      0u          // G' fp32 [4096][128] = 2 MiB
#define OFF_GSTATS 2097152u    // float4 per j        = 64 KiB
#define OFF_SCAL   2162688u    // {mean(w0), mean(w0^2)}
#define OFF_W0C    2162944u    // fp32[128]
#define OFF_C3     2163456u    // fp32[128] (= hbt1)
#define OFF_W2F    2163968u    // uint4[16][64] bf16 B-frags = 16 KiB
#define OFF_POOL   2180352u    // fp32[128][64]
#define OFF_CNT    2213120u    // fp32[128]

static __device__ __forceinline__ unsigned pk2(float a, float b) {
    __hip_bfloat162 t = __float22bfloat162_rn(make_float2(a, b));
    union { __hip_bfloat162 h; unsigned u; } c; c.h = t; return c.u;
}

// ---------------------------------------------------------------------------
// g_kernel: G[j,h] = hb1[h] + F[j,:]@hW1[1:,h]; write centered-scaled
// G'[j,h] = (G - mean_h(G_j)) * hg1[h]; Gstats[j] = {mG, mean(w0*G), mean(G^2)};
// block j==0 also writes {mean(w0), mean(w0^2)}.
// ---------------------------------------------------------------------------
__global__ __launch_bounds__(128) void g_kernel(
    const float* __restrict__ F, const float* __restrict__ hW1,
    const float* __restrict__ hb1, const float* __restrict__ hg1,
    float* __restrict__ Gp, float4* __restrict__ Gstats,
    float* __restrict__ scal)
{
    const int j = blockIdx.x;
    const int h = threadIdx.x;
    const float* frow = F + (size_t)j * D_;
    float acc = hb1[h];
#pragma unroll
    for (int d = 0; d < D_; d++)
        acc = fmaf(frow[d], hW1[(d + 1) * H_ + h], acc);

    const float w0h = hW1[h];
    float s1 = acc, s2 = w0h * acc, s3 = acc * acc, s4 = w0h, s5 = w0h * w0h;
#pragma unroll
    for (int off = 32; off; off >>= 1) {
        s1 += __shfl_xor(s1, off);
        s2 += __shfl_xor(s2, off);
        s3 += __shfl_xor(s3, off);
        s4 += __shfl_xor(s4, off);
        s5 += __shfl_xor(s5, off);
    }
    __shared__ float red[10];
    if ((h & 63) == 0) {
        int w = h >> 6;
        red[w*5+0]=s1; red[w*5+1]=s2; red[w*5+2]=s3; red[w*5+3]=s4; red[w*5+4]=s5;
    }
    __syncthreads();
    const float inv = 1.f / (float)H_;
    const float mG = (red[0] + red[5]) * inv;
    if (h == 0) {
        Gstats[j] = make_float4(mG, (red[1]+red[6])*inv, (red[2]+red[7])*inv, 0.f);
        if (j == 0) { scal[0] = (red[3]+red[8])*inv; scal[1] = (red[4]+red[9])*inv; }
    }
    Gp[j * H_ + h] = (acc - mG) * hg1[h];
}

// ---------------------------------------------------------------------------
// prep_kernel: w0c[h]=(w0[h]-mw0)*g1[h]; c3[h]=bt1[h]; pack W2 into bf16
// B-fragments for mfma_f32_16x16x32_bf16: frag f=(kstep*4+nt), lane l holds
// B[k = kstep*32 + (l>>4)*8 + i][n = nt*16 + (l&15)], i=0..7.
// ---------------------------------------------------------------------------
__global__ __launch_bounds__(128) void prep_kernel(
    const float* __restrict__ hW1, const float* __restrict__ hg1,
    const float* __restrict__ hbt1, const float* __restrict__ hW2,
    const float* __restrict__ scal,
    float* __restrict__ w0c, float* __restrict__ c3,
    uint4* __restrict__ w2f)
{
    const int t = threadIdx.x;
    const float mw0 = scal[0];
    w0c[t] = (hW1[t] - mw0) * hg1[t];
    c3[t]  = hbt1[t];

    const int lane = t & 63, half = t >> 6;
    const int quad = lane >> 4, col = lane & 15;
    for (int f = half; f < 16; f += 2) {
        const int kstep = f >> 2, nt = f & 3;
        const int kbase = kstep * 32 + quad * 8;
        const int n = nt * 16 + col;
        unsigned r[4];
#pragma unroll
        for (int p = 0; p < 4; p++)
            r[p] = pk2(hW2[(kbase + 2*p) * D_ + n], hW2[(kbase + 2*p + 1) * D_ + n]);
        w2f[f * 64 + lane] = make_uint4(r[0], r[1], r[2], r[3]);
    }
}

// ---------------------------------------------------------------------------
// main_kernel: per (b, 16-row j-tile): build H-tile in A-frag layout with
// 3 VALU/elem LN1 closed form, MFMA vs register-held W2 B-frags,
// LN2 from C-layout via 16-lane xor-shuffles, masked pool accumulate.
// Block = 256 threads (4 independent waves), TPW tiles per wave.
// ---------------------------------------------------------------------------
#define TPW 4

__global__ __launch_bounds__(256, 2) void main_kernel(
    const float* __restrict__ x, const int* __restrict__ mask,
    const float* __restrict__ Gp, const float4* __restrict__ Gstats,
    const float* __restrict__ scal,
    const float* __restrict__ w0c, const float* __restrict__ c3,
    const uint4* __restrict__ w2f,
    const float* __restrict__ hb2, const float* __restrict__ hg2,
    const float* __restrict__ hbt2,
    float* __restrict__ pooled, float* __restrict__ cnt)
{
    const int tid  = threadIdx.x;
    const int lane = tid & 63;
    const int wv   = tid >> 6;
    const int b    = blockIdx.y;
    const int quad = lane >> 4;
    const int col  = lane & 15;

    // ---- per-wave preload ----
    short8 w2r[16];
#pragma unroll
    for (int f = 0; f < 16; f++) {
        uint4 u = w2f[f * 64 + lane];
        union { uint4 v; short8 s; } c; c.v = u;
        w2r[f] = c.s;
    }
    float4 wc[4][2], cc[4][2];
#pragma unroll
    for (int k = 0; k < 4; k++) {
        wc[k][0] = ((const float4*)(w0c + k*32 + quad*8))[0];
        wc[k][1] = ((const float4*)(w0c + k*32 + quad*8))[1];
        cc[k][0] = ((const float4*)(c3  + k*32 + quad*8))[0];
        cc[k][1] = ((const float4*)(c3  + k*32 + quad*8))[1];
    }
    float hb2v[4], g2v[4], bt2v[4];
#pragma unroll
    for (int nt = 0; nt < 4; nt++) {
        hb2v[nt] = hb2[nt*16 + col];
        g2v[nt]  = hg2[nt*16 + col];
        bt2v[nt] = hbt2[nt*16 + col];
    }
    const float mw0s  = scal[0];
    const float ew02s = scal[1];

    float pool0 = 0.f, pool1 = 0.f, pool2 = 0.f, pool3 = 0.f, cn = 0.f;

    for (int t = 0; t < TPW; t++) {
        const int tIdx = (blockIdx.x * 4 + wv) * TPW + t;
        const int j0   = tIdx * 16;
        const int rowA = j0 + col;

        const float  xA = x[b * J_ + rowA];
        const float4 gs = Gstats[rowA];
        const float mean = fmaf(xA, mw0s, gs.x);
        const float eh2  = fmaf(xA, fmaf(xA, ew02s, 2.f * gs.y), gs.z);
        const float r1   = rsqrtf(fmaf(-mean, mean, eh2) + 1e-5f);

        const float* gpr = Gp + rowA * H_ + quad * 8;
        float4 ga[4][2];
#pragma unroll
        for (int k = 0; k < 4; k++) {
            ga[k][0] = ((const float4*)(gpr + k*32))[0];
            ga[k][1] = ((const float4*)(gpr + k*32))[1];
        }
        const int4 mk4 = *(const int4*)(mask + b * J_ + j0 + quad * 4);

        floatx4 acc0 = {0.f,0.f,0.f,0.f}, acc1 = {0.f,0.f,0.f,0.f};
        floatx4 acc2 = {0.f,0.f,0.f,0.f}, acc3 = {0.f,0.f,0.f,0.f};

#pragma unroll
        for (int k = 0; k < 4; k++) {
            const float h0 = fmaxf(0.f, fmaf(fmaf(xA, wc[k][0].x, ga[k][0].x), r1, cc[k][0].x));
            const float h1 = fmaxf(0.f, fmaf(fmaf(xA, wc[k][0].y, ga[k][0].y), r1, cc[k][0].y));
            const float h2 = fmaxf(0.f, fmaf(fmaf(xA, wc[k][0].z, ga[k][0].z), r1, cc[k][0].z));
            const float h3 = fmaxf(0.f, fmaf(fmaf(xA, wc[k][0].w, ga[k][0].w), r1, cc[k][0].w));
            const float h4 = fmaxf(0.f, fmaf(fmaf(xA, wc[k][1].x, ga[k][1].x), r1, cc[k][1].x));
            const float h5 = fmaxf(0.f, fmaf(fmaf(xA, wc[k][1].y, ga[k][1].y), r1, cc[k][1].y));
            const float h6 = fmaxf(0.f, fmaf(fmaf(xA, wc[k][1].z, ga[k][1].z), r1, cc[k][1].z));
            const float h7 = fmaxf(0.f, fmaf(fmaf(xA, wc[k][1].w, ga[k][1].w), r1, cc[k][1].w));
            union { unsigned u[4]; short8 s; } af;
            af.u[0] = pk2(h0, h1);
            af.u[1] = pk2(h2, h3);
            af.u[2] = pk2(h4, h5);
            af.u[3] = pk2(h6, h7);
            acc0 = __builtin_amdgcn_mfma_f32_16x16x32_bf16(af.s, w2r[k*4+0], acc0, 0, 0, 0);
            acc1 = __builtin_amdgcn_mfma_f32_16x16x32_bf16(af.s, w2r[k*4+1], acc1, 0, 0, 0);
            acc2 = __builtin_amdgcn_mfma_f32_16x16x32_bf16(af.s, w2r[k*4+2], acc2, 0, 0, 0);
            acc3 = __builtin_amdgcn_mfma_f32_16x16x32_bf16(af.s, w2r[k*4+3], acc3, 0, 0, 0);
        }

        // ---- epilogue: bias, LN2 stats over d=64, relu, masked pool ----
        float sa[4], qa[4];
#pragma unroll
        for (int r = 0; r < 4; r++) {
            const float v0 = acc0[r] + hb2v[0];
            const float v1 = acc1[r] + hb2v[1];
            const float v2 = acc2[r] + hb2v[2];
            const float v3 = acc3[r] + hb2v[3];
            acc0[r] = v0; acc1[r] = v1; acc2[r] = v2; acc3[r] = v3;
            sa[r] = (v0 + v1) + (v2 + v3);
            qa[r] = fmaf(v0, v0, fmaf(v1, v1, fmaf(v2, v2, v3 * v3)));
        }
#pragma unroll
        for (int m = 1; m < 16; m <<= 1) {
#pragma unroll
            for (int r = 0; r < 4; r++) {
                sa[r] += __shfl_xor(sa[r], m);
                qa[r] += __shfl_xor(qa[r], m);
            }
        }
        float mr[4];
        mr[0] = (mk4.x > 0) ? 1.f : 0.f;
        mr[1] = (mk4.y > 0) ? 1.f : 0.f;
        mr[2] = (mk4.z > 0) ? 1.f : 0.f;
        mr[3] = (mk4.w > 0) ? 1.f : 0.f;
#pragma unroll
        for (int r = 0; r < 4; r++) {
            const float m2 = sa[r] * (1.f / 64.f);
            const float v2 = fmaf(-m2, m2, qa[r] * (1.f / 64.f));
            const float r2 = rsqrtf(v2 + 1e-5f);
            const float o0 = fmaxf(0.f, fmaf((acc0[r] - m2) * r2, g2v[0], bt2v[0]));
            const float o1 = fmaxf(0.f, fmaf((acc1[r] - m2) * r2, g2v[1], bt2v[1]));
            const float o2 = fmaxf(0.f, fmaf((acc2[r] - m2) * r2, g2v[2], bt2v[2]));
            const float o3 = fmaxf(0.f, fmaf((acc3[r] - m2) * r2, g2v[3], bt2v[3]));
            pool0 = fmaf(mr[r], o0, pool0);
            pool1 = fmaf(mr[r], o1, pool1);
            pool2 = fmaf(mr[r], o2, pool2);
            pool3 = fmaf(mr[r], o3, pool3);
        }
        cn += (mr[0] + mr[1]) + (mr[2] + mr[3]);
    }

    // reduce over the 4 quad-groups (rows) and write
#pragma unroll
    for (int m = 16; m < 64; m <<= 1) {
        pool0 += __shfl_xor(pool0, m);
        pool1 += __shfl_xor(pool1, m);
        pool2 += __shfl_xor(pool2, m);
        pool3 += __shfl_xor(pool3, m);
        cn    += __shfl_xor(cn, m);
    }
    if (lane < 16) {
        atomicAdd(&pooled[b * D_ +  0 + lane], pool0);
        atomicAdd(&pooled[b * D_ + 16 + lane], pool1);
        atomicAdd(&pooled[b * D_ + 32 + lane], pool2);
        atomicAdd(&pooled[b * D_ + 48 + lane], pool3);
        if (lane == 0) atomicAdd(&cnt[b], cn);
    }
}

// ---------------------------------------------------------------------------
// final_kernel: per-b head (unchanged from round 1, verified correct)
// ---------------------------------------------------------------------------
__global__ __launch_bounds__(256) void final_kernel(
    const float* __restrict__ pooled, const float* __restrict__ cntg,
    const float* __restrict__ eW1, const float* __restrict__ eb1,
    const float* __restrict__ eW2, const float* __restrict__ eb2,
    float* __restrict__ out)
{
    __shared__ float c_lds[D_];
    __shared__ float e_lds[E_];
    __shared__ float red[8];
    const int b = blockIdx.x;
    const int t = threadIdx.x;

    if (t < D_) {
        float cn = fmaxf(cntg[b], 1.f);
        c_lds[t] = pooled[(size_t)b * D_ + t] / cn;
    }
    __syncthreads();

    float acc = eb1[t];
#pragma unroll
    for (int d = 0; d < D_; d++)
        acc = fmaf(c_lds[d], eW1[(size_t)d * E_ + t], acc);

    float s = acc, s2 = acc * acc;
#pragma unroll
    for (int off = 32; off; off >>= 1) {
        s  += __shfl_xor(s, off);
        s2 += __shfl_xor(s2, off);
    }
    const int wid = t >> 6;
    if ((t & 63) == 0) { red[wid * 2] = s; red[wid * 2 + 1] = s2; }
    __syncthreads();
    s  = red[0] + red[2] + red[4] + red[6];
    s2 = red[1] + red[3] + red[5] + red[7];
    const float m = s * (1.f / (float)E_);
    const float v = fmaf(-m, m, s2 * (1.f / (float)E_));
    const float r = rsqrtf(v + 1e-5f);
    e_lds[t] = fmaxf(0.f, (acc - m) * r);
    __syncthreads();

    if (t < 64) {
        float a2 = eb2[t];
#pragma unroll 8
        for (int k = 0; k < E_; k++)
            a2 = fmaf(e_lds[k], eW2[(size_t)k * 64 + t], a2);

        float u = a2, u2 = a2 * a2;
#pragma unroll
        for (int off = 32; off; off >>= 1) {
            u  += __shfl_xor(u, off);
            u2 += __shfl_xor(u2, off);
        }
        const float m2 = u * (1.f / 64.f);
        const float v2 = fmaf(-m2, m2, u2 * (1.f / 64.f));
        const float r2 = rsqrtf(v2 + 1e-5f);
        const float o  = fmaxf(0.f, (a2 - m2) * r2);
        if (t < Z_) out[(size_t)b * Z_ + t] = o;
        else        out[(size_t)B_ * Z_ + (size_t)b * Z_ + (t - Z_)] = o;
    }
}

// ---------------------------------------------------------------------------
extern "C" void kernel_launch(void* const* d_in, const int* in_sizes, int n_in,
                              void* d_out, int out_size, void* d_ws, size_t ws_size,
                              hipStream_t stream) {
    const float* x    = (const float*)d_in[0];
    const int*   mask = (const int*)d_in[1];
    const float* F    = (const float*)d_in[2];
    const float* hW1  = (const float*)d_in[3];
    const float* hb1  = (const float*)d_in[4];
    const float* hg1  = (const float*)d_in[5];
    const float* hbt1 = (const float*)d_in[6];
    const float* hW2  = (const float*)d_in[7];
    const float* hb2  = (const float*)d_in[8];
    const float* hg2  = (const float*)d_in[9];
    const float* hbt2 = (const float*)d_in[10];
    const float* eW1  = (const float*)d_in[11];
    const float* eb1  = (const float*)d_in[12];
    const float* eW2  = (const float*)d_in[13];
    const float* eb2  = (const float*)d_in[14];
    float* out = (float*)d_out;

    char* ws = (char*)d_ws;
    float*  Gp     = (float*)(ws + OFF_G);
    float4* Gstats = (float4*)(ws + OFF_GSTATS);
    float*  scal   = (float*)(ws + OFF_SCAL);
    float*  w0c    = (float*)(ws + OFF_W0C);
    float*  c3     = (float*)(ws + OFF_C3);
    uint4*  w2f    = (uint4*)(ws + OFF_W2F);
    float*  pooled = (float*)(ws + OFF_POOL);
    float*  cnt    = (float*)(ws + OFF_CNT);

    hipMemsetAsync(pooled, 0, (size_t)B_ * D_ * 4 + 512, stream);

    g_kernel<<<J_, 128, 0, stream>>>(F, hW1, hb1, hg1, Gp, Gstats, scal);
    prep_kernel<<<1, 128, 0, stream>>>(hW1, hg1, hbt1, hW2, scal, w0c, c3, w2f);
    main_kernel<<<dim3(J_ / (16 * 4 * TPW), B_), 256, 0, stream>>>(
        x, mask, Gp, Gstats, scal, w0c, c3, w2f, hb2, hg2, hbt2, pooled, cnt);
    final_kernel<<<B_, E_, 0, stream>>>(pooled, cnt, eW1, eb1, eW2, eb2, out);
}

// Round 3
// 141.952 us; speedup vs baseline: 2.8420x; 1.2244x over previous
//
#include <hip/hip_runtime.h>
#include <hip/hip_bf16.h>

#define B_  128
#define J_  4096
#define D_  64
#define H_  128
#define E_  256
#define Z_  32

typedef __attribute__((ext_vector_type(8))) short short8;    // 8 bf16 (4 VGPRs)
typedef __attribute__((ext_vector_type(4))) float floatx4;   // MFMA C/D

// workspace layout (bytes)
#define OFF_G      0u          // G' fp32 [4096][128] = 2 MiB
#define OFF_GSTATS 2097152u    // float4 per j        = 64 KiB
#define OFF_SCAL   2162688u    // {mean(w0), mean(w0^2)}
#define OFF_W0C    2162944u    // fp32[128]
#define OFF_C3     2163456u    // fp32[128] (= hbt1)
#define OFF_W2F    2163968u    // uint4[16][64] bf16 B-frags = 16 KiB
#define OFF_POOL   2180352u    // fp32[128][64] = 32 KiB

static __device__ __forceinline__ unsigned pk2(float a, float b) {
    __hip_bfloat162 t = __float22bfloat162_rn(make_float2(a, b));
    union { __hip_bfloat162 h; unsigned u; } c; c.h = t; return c.u;
}

// ---------------------------------------------------------------------------
// g_kernel: G[j,h] = hb1[h] + F[j,:]@hW1[1:,h]; writes
// G'[j,h] = (G - mean_h(G_j)) * hg1[h]; Gstats[j] = {mG, mean(w0*G), mean(G^2)}.
// 4-way split accumulators to break the fma dependency chain.
// ---------------------------------------------------------------------------
__global__ __launch_bounds__(128) void g_kernel(
    const float* __restrict__ F, const float* __restrict__ hW1,
    const float* __restrict__ hb1, const float* __restrict__ hg1,
    float* __restrict__ Gp, float4* __restrict__ Gstats)
{
    const int j = blockIdx.x;
    const int h = threadIdx.x;
    const float* frow = F + (size_t)j * D_;
    float a0 = hb1[h], a1 = 0.f, a2 = 0.f, a3 = 0.f;
#pragma unroll
    for (int d = 0; d < D_; d += 4) {
        a0 = fmaf(frow[d + 0], hW1[(d + 1) * H_ + h], a0);
        a1 = fmaf(frow[d + 1], hW1[(d + 2) * H_ + h], a1);
        a2 = fmaf(frow[d + 2], hW1[(d + 3) * H_ + h], a2);
        a3 = fmaf(frow[d + 3], hW1[(d + 4) * H_ + h], a3);
    }
    const float acc = (a0 + a1) + (a2 + a3);

    const float w0h = hW1[h];
    float s1 = acc, s2 = w0h * acc, s3 = acc * acc;
#pragma unroll
    for (int off = 32; off; off >>= 1) {
        s1 += __shfl_xor(s1, off);
        s2 += __shfl_xor(s2, off);
        s3 += __shfl_xor(s3, off);
    }
    __shared__ float red[6];
    if ((h & 63) == 0) {
        int w = h >> 6;
        red[w*3+0] = s1; red[w*3+1] = s2; red[w*3+2] = s3;
    }
    __syncthreads();
    const float inv = 1.f / (float)H_;
    const float mG = (red[0] + red[3]) * inv;
    if (h == 0)
        Gstats[j] = make_float4(mG, (red[1]+red[4])*inv, (red[2]+red[5])*inv, 0.f);
    Gp[j * H_ + h] = (acc - mG) * hg1[h];
}

// ---------------------------------------------------------------------------
// prep_kernel (9 blocks x 256):
//  block 0: scal = {mean(w0), mean(w0^2)}; w0c = (w0-mw0)*g1; c3 = bt1;
//           pack W2 into bf16 B-frags (frag f = kstep*4+nt; lane holds
//           B[k=kstep*32+(l>>4)*8+i][n=nt*16+(l&15)], i=0..7).
//  blocks 1..8: zero pooled (replaces the memset dispatch).
// ---------------------------------------------------------------------------
__global__ __launch_bounds__(256) void prep_kernel(
    const float* __restrict__ hW1, const float* __restrict__ hg1,
    const float* __restrict__ hbt1, const float* __restrict__ hW2,
    float* __restrict__ scal, float* __restrict__ w0c, float* __restrict__ c3,
    uint4* __restrict__ w2f, float4* __restrict__ pooled4)
{
    const int t = threadIdx.x;
    if (blockIdx.x > 0) {
        pooled4[(blockIdx.x - 1) * 256 + t] = make_float4(0.f, 0.f, 0.f, 0.f);
        return;
    }

    __shared__ float sred[4];
    if (t < H_) {
        const float w0h = hW1[t];
        float s = w0h, q = w0h * w0h;
#pragma unroll
        for (int off = 32; off; off >>= 1) {
            s += __shfl_xor(s, off);
            q += __shfl_xor(q, off);
        }
        if ((t & 63) == 0) { sred[(t >> 6) * 2] = s; sred[(t >> 6) * 2 + 1] = q; }
    }
    __syncthreads();
    const float mw0  = (sred[0] + sred[2]) * (1.f / (float)H_);
    const float ew02 = (sred[1] + sred[3]) * (1.f / (float)H_);
    if (t == 0) { scal[0] = mw0; scal[1] = ew02; }
    if (t < H_) {
        w0c[t] = (hW1[t] - mw0) * hg1[t];
        c3[t]  = hbt1[t];
    }

    const int lane = t & 63, wq = t >> 6;
    const int quad = lane >> 4, col = lane & 15;
    for (int f = wq; f < 16; f += 4) {
        const int kstep = f >> 2, nt = f & 3;
        const int kbase = kstep * 32 + quad * 8;
        const int n = nt * 16 + col;
        unsigned r[4];
#pragma unroll
        for (int p = 0; p < 4; p++)
            r[p] = pk2(hW2[(kbase + 2*p) * D_ + n], hW2[(kbase + 2*p + 1) * D_ + n]);
        w2f[f * 64 + lane] = make_uint4(r[0], r[1], r[2], r[3]);
    }
}

// ---------------------------------------------------------------------------
// main_kernel: per (b-group of BB, 16-row j-tile): tile loads (Gp, Gstats)
// amortized over BB batch rows; per b: 3-op/elem LN1 closed-form H build in
// A-frag layout, 16 MFMA vs register-held W2 B-frags, LN2 from C-layout via
// 16-lane xor shuffles, masked pool accumulation in registers.
// ---------------------------------------------------------------------------
#define TPW 2
#define BB  4

__global__ __launch_bounds__(256, 2) void main_kernel(
    const float* __restrict__ x, const int* __restrict__ mask,
    const float* __restrict__ Gp, const float4* __restrict__ Gstats,
    const float* __restrict__ scal,
    const float* __restrict__ w0c, const float* __restrict__ c3,
    const uint4* __restrict__ w2f,
    const float* __restrict__ hb2, const float* __restrict__ hg2,
    const float* __restrict__ hbt2,
    float* __restrict__ pooled)
{
    const int tid  = threadIdx.x;
    const int lane = tid & 63;
    const int wv   = tid >> 6;
    const int quad = lane >> 4;
    const int col  = lane & 15;
    const int b0   = blockIdx.y * BB;

    // ---- per-wave preload ----
    short8 w2r[16];
#pragma unroll
    for (int f = 0; f < 16; f++) {
        union { uint4 v; short8 s; } c; c.v = w2f[f * 64 + lane];
        w2r[f] = c.s;
    }
    float4 wc[4][2], cc[4][2];
#pragma unroll
    for (int k = 0; k < 4; k++) {
        wc[k][0] = ((const float4*)(w0c + k*32 + quad*8))[0];
        wc[k][1] = ((const float4*)(w0c + k*32 + quad*8))[1];
        cc[k][0] = ((const float4*)(c3  + k*32 + quad*8))[0];
        cc[k][1] = ((const float4*)(c3  + k*32 + quad*8))[1];
    }
    float hb2v[4], g2v[4], bt2v[4];
#pragma unroll
    for (int nt = 0; nt < 4; nt++) {
        hb2v[nt] = hb2[nt*16 + col];
        g2v[nt]  = hg2[nt*16 + col];
        bt2v[nt] = hbt2[nt*16 + col];
    }
    const float mw0s  = scal[0];
    const float ew02s = scal[1];

    float pool[BB][4];
#pragma unroll
    for (int bb = 0; bb < BB; bb++)
#pragma unroll
        for (int nt = 0; nt < 4; nt++) pool[bb][nt] = 0.f;

    for (int t = 0; t < TPW; t++) {
        const int tIdx = (blockIdx.x * 4 + wv) * TPW + t;
        const int j0   = tIdx * 16;
        const int rowA = j0 + col;

        // ---- tile loads (shared across BB batch rows) ----
        const float4 gs = Gstats[rowA];
        float xv[BB]; int4 mk[BB];
#pragma unroll
        for (int bb = 0; bb < BB; bb++) {
            xv[bb] = x[(size_t)(b0 + bb) * J_ + rowA];
            mk[bb] = *(const int4*)(mask + (size_t)(b0 + bb) * J_ + j0 + quad * 4);
        }
        const float* gpr = Gp + rowA * H_ + quad * 8;
        float4 ga[4][2];
#pragma unroll
        for (int k = 0; k < 4; k++) {
            ga[k][0] = ((const float4*)(gpr + k*32))[0];
            ga[k][1] = ((const float4*)(gpr + k*32))[1];
        }

#pragma unroll
        for (int bb = 0; bb < BB; bb++) {
            const float xA = xv[bb];
            const float mean = fmaf(xA, mw0s, gs.x);
            const float eh2  = fmaf(xA, fmaf(xA, ew02s, 2.f * gs.y), gs.z);
            const float r1   = rsqrtf(fmaf(-mean, mean, eh2) + 1e-5f);

            floatx4 acc[4];
#pragma unroll
            for (int nt = 0; nt < 4; nt++) acc[nt] = (floatx4){0.f, 0.f, 0.f, 0.f};

#pragma unroll
            for (int k = 0; k < 4; k++) {
                const float h0 = fmaxf(0.f, fmaf(fmaf(xA, wc[k][0].x, ga[k][0].x), r1, cc[k][0].x));
                const float h1 = fmaxf(0.f, fmaf(fmaf(xA, wc[k][0].y, ga[k][0].y), r1, cc[k][0].y));
                const float h2 = fmaxf(0.f, fmaf(fmaf(xA, wc[k][0].z, ga[k][0].z), r1, cc[k][0].z));
                const float h3 = fmaxf(0.f, fmaf(fmaf(xA, wc[k][0].w, ga[k][0].w), r1, cc[k][0].w));
                const float h4 = fmaxf(0.f, fmaf(fmaf(xA, wc[k][1].x, ga[k][1].x), r1, cc[k][1].x));
                const float h5 = fmaxf(0.f, fmaf(fmaf(xA, wc[k][1].y, ga[k][1].y), r1, cc[k][1].y));
                const float h6 = fmaxf(0.f, fmaf(fmaf(xA, wc[k][1].z, ga[k][1].z), r1, cc[k][1].z));
                const float h7 = fmaxf(0.f, fmaf(fmaf(xA, wc[k][1].w, ga[k][1].w), r1, cc[k][1].w));
                union { unsigned u[4]; short8 s; } af;
                af.u[0] = pk2(h0, h1);
                af.u[1] = pk2(h2, h3);
                af.u[2] = pk2(h4, h5);
                af.u[3] = pk2(h6, h7);
                acc[0] = __builtin_amdgcn_mfma_f32_16x16x32_bf16(af.s, w2r[k*4+0], acc[0], 0, 0, 0);
                acc[1] = __builtin_amdgcn_mfma_f32_16x16x32_bf16(af.s, w2r[k*4+1], acc[1], 0, 0, 0);
                acc[2] = __builtin_amdgcn_mfma_f32_16x16x32_bf16(af.s, w2r[k*4+2], acc[2], 0, 0, 0);
                acc[3] = __builtin_amdgcn_mfma_f32_16x16x32_bf16(af.s, w2r[k*4+3], acc[3], 0, 0, 0);
            }

            // ---- epilogue: bias, LN2 over d=64, relu, masked pool ----
            float sa[4], qa[4];
#pragma unroll
            for (int r = 0; r < 4; r++) {
                const float v0 = acc[0][r] + hb2v[0];
                const float v1 = acc[1][r] + hb2v[1];
                const float v2 = acc[2][r] + hb2v[2];
                const float v3 = acc[3][r] + hb2v[3];
                acc[0][r] = v0; acc[1][r] = v1; acc[2][r] = v2; acc[3][r] = v3;
                sa[r] = (v0 + v1) + (v2 + v3);
                qa[r] = fmaf(v0, v0, fmaf(v1, v1, fmaf(v2, v2, v3 * v3)));
            }
#pragma unroll
            for (int m = 1; m < 16; m <<= 1) {
#pragma unroll
                for (int r = 0; r < 4; r++) {
                    sa[r] += __shfl_xor(sa[r], m);
                    qa[r] += __shfl_xor(qa[r], m);
                }
            }
            float mrr[4];
            mrr[0] = (mk[bb].x > 0) ? 1.f : 0.f;
            mrr[1] = (mk[bb].y > 0) ? 1.f : 0.f;
            mrr[2] = (mk[bb].z > 0) ? 1.f : 0.f;
            mrr[3] = (mk[bb].w > 0) ? 1.f : 0.f;
#pragma unroll
            for (int r = 0; r < 4; r++) {
                const float m2 = sa[r] * (1.f / 64.f);
                const float v2 = fmaf(-m2, m2, qa[r] * (1.f / 64.f));
                const float r2 = rsqrtf(v2 + 1e-5f);
#pragma unroll
                for (int nt = 0; nt < 4; nt++) {
                    const float rg  = r2 * g2v[nt];
                    const float off = fmaf(-m2, rg, bt2v[nt]);
                    const float o   = fmaxf(0.f, fmaf(acc[nt][r], rg, off));
                    pool[bb][nt] = fmaf(mrr[r], o, pool[bb][nt]);
                }
            }
        }
    }

    // reduce pools over the 4 quad-groups and write
#pragma unroll
    for (int m = 16; m < 64; m <<= 1)
#pragma unroll
        for (int bb = 0; bb < BB; bb++)
#pragma unroll
            for (int nt = 0; nt < 4; nt++)
                pool[bb][nt] += __shfl_xor(pool[bb][nt], m);

    if (lane < 16) {
#pragma unroll
        for (int bb = 0; bb < BB; bb++)
#pragma unroll
            for (int nt = 0; nt < 4; nt++)
                atomicAdd(&pooled[(size_t)(b0 + bb) * D_ + nt * 16 + lane], pool[bb][nt]);
    }
}

// ---------------------------------------------------------------------------
// final_kernel: per-b head; also computes cnt[b] by summing the mask row.
// ---------------------------------------------------------------------------
__global__ __launch_bounds__(256) void final_kernel(
    const float* __restrict__ pooled, const int* __restrict__ mask,
    const float* __restrict__ eW1, const float* __restrict__ eb1,
    const float* __restrict__ eW2, const float* __restrict__ eb2,
    float* __restrict__ out)
{
    __shared__ float c_lds[D_];
    __shared__ float e_lds[E_];
    __shared__ float red[8];
    __shared__ float redc[4];
    const int b = blockIdx.x;
    const int t = threadIdx.x;
    const int lane = t & 63, wid = t >> 6;

    // count observed entries in this row
    {
        const int4* mrow = (const int4*)(mask + (size_t)b * J_);
        int s = 0;
#pragma unroll
        for (int i = 0; i < 4; i++) {
            const int4 v = mrow[t * 4 + i];
            s += (v.x > 0) + (v.y > 0) + (v.z > 0) + (v.w > 0);
        }
        float fs = (float)s;
#pragma unroll
        for (int off = 32; off; off >>= 1) fs += __shfl_xor(fs, off);
        if (lane == 0) redc[wid] = fs;
    }
    __syncthreads();
    const float cn = fmaxf((redc[0] + redc[1]) + (redc[2] + redc[3]), 1.f);
    if (t < D_) c_lds[t] = pooled[(size_t)b * D_ + t] / cn;
    __syncthreads();

    // layer 1: 64 -> 256
    float acc = eb1[t];
#pragma unroll
    for (int d = 0; d < D_; d++)
        acc = fmaf(c_lds[d], eW1[(size_t)d * E_ + t], acc);

    float s = acc, s2 = acc * acc;
#pragma unroll
    for (int off = 32; off; off >>= 1) {
        s  += __shfl_xor(s, off);
        s2 += __shfl_xor(s2, off);
    }
    if ((t & 63) == 0) { red[wid * 2] = s; red[wid * 2 + 1] = s2; }
    __syncthreads();
    s  = red[0] + red[2] + red[4] + red[6];
    s2 = red[1] + red[3] + red[5] + red[7];
    const float m = s * (1.f / (float)E_);
    const float v = fmaf(-m, m, s2 * (1.f / (float)E_));
    const float r = rsqrtf(v + 1e-5f);
    e_lds[t] = fmaxf(0.f, (acc - m) * r);
    __syncthreads();

    // layer 2: 256 -> 64, first wave only
    if (t < 64) {
        float a2 = eb2[t];
#pragma unroll 8
        for (int k = 0; k < E_; k++)
            a2 = fmaf(e_lds[k], eW2[(size_t)k * 64 + t], a2);

        float u = a2, u2 = a2 * a2;
#pragma unroll
        for (int off = 32; off; off >>= 1) {
            u  += __shfl_xor(u, off);
            u2 += __shfl_xor(u2, off);
        }
        const float m2 = u * (1.f / 64.f);
        const float v2 = fmaf(-m2, m2, u2 * (1.f / 64.f));
        const float r2 = rsqrtf(v2 + 1e-5f);
        const float o  = fmaxf(0.f, (a2 - m2) * r2);
        if (t < Z_) out[(size_t)b * Z_ + t] = o;
        else        out[(size_t)B_ * Z_ + (size_t)b * Z_ + (t - Z_)] = o;
    }
}

// ---------------------------------------------------------------------------
extern "C" void kernel_launch(void* const* d_in, const int* in_sizes, int n_in,
                              void* d_out, int out_size, void* d_ws, size_t ws_size,
                              hipStream_t stream) {
    const float* x    = (const float*)d_in[0];
    const int*   mask = (const int*)d_in[1];
    const float* F    = (const float*)d_in[2];
    const float* hW1  = (const float*)d_in[3];
    const float* hb1  = (const float*)d_in[4];
    const float* hg1  = (const float*)d_in[5];
    const float* hbt1 = (const float*)d_in[6];
    const float* hW2  = (const float*)d_in[7];
    const float* hb2  = (const float*)d_in[8];
    const float* hg2  = (const float*)d_in[9];
    const float* hbt2 = (const float*)d_in[10];
    const float* eW1  = (const float*)d_in[11];
    const float* eb1  = (const float*)d_in[12];
    const float* eW2  = (const float*)d_in[13];
    const float* eb2  = (const float*)d_in[14];
    float* out = (float*)d_out;

    char* ws = (char*)d_ws;
    float*  Gp     = (float*)(ws + OFF_G);
    float4* Gstats = (float4*)(ws + OFF_GSTATS);
    float*  scal   = (float*)(ws + OFF_SCAL);
    float*  w0c    = (float*)(ws + OFF_W0C);
    float*  c3     = (float*)(ws + OFF_C3);
    uint4*  w2f    = (uint4*)(ws + OFF_W2F);
    float*  pooled = (float*)(ws + OFF_POOL);

    g_kernel<<<J_, 128, 0, stream>>>(F, hW1, hb1, hg1, Gp, Gstats);
    prep_kernel<<<9, 256, 0, stream>>>(hW1, hg1, hbt1, hW2, scal, w0c, c3, w2f,
                                       (float4*)pooled);
    main_kernel<<<dim3(J_ / (16 * 4 * TPW), B_ / BB), 256, 0, stream>>>(
        x, mask, Gp, Gstats, scal, w0c, c3, w2f, hb2, hg2, hbt2, pooled);
    final_kernel<<<B_, E_, 0, stream>>>(pooled, mask, eW1, eb1, eW2, eb2, out);
}